// Round 1
// baseline (235.782 us; speedup 1.0000x reference)
//
#include <hip/hip_runtime.h>

// ---------- common helpers ----------
typedef __attribute__((ext_vector_type(8))) unsigned short ushort8v;
typedef __attribute__((ext_vector_type(8))) __bf16 bf16x8;
typedef __attribute__((ext_vector_type(4))) float floatx4;

__device__ __forceinline__ unsigned short f2b(float f) {
    unsigned u = __float_as_uint(f);
    unsigned r = u + 0x7fffu + ((u >> 16) & 1u);   // RNE; inputs are finite/small
    return (unsigned short)(r >> 16);
}
__device__ __forceinline__ float b2f(unsigned short h) {
    return __uint_as_float(((unsigned)h) << 16);
}

__device__ __forceinline__ void async_cp16(const void* g, void* l) {
    __builtin_amdgcn_global_load_lds(
        (__attribute__((address_space(1))) void*)g,
        (__attribute__((address_space(3))) void*)l,
        16, 0, 0);
}

// ---------- x fp32 -> bf16 ----------
__global__ __launch_bounds__(256) void cvt_f32_bf16(const float* __restrict__ in,
                                                    unsigned short* __restrict__ out,
                                                    int n4) {
    int i = blockIdx.x * 256 + threadIdx.x;
    if (i < n4) {
        float4 v = ((const float4*)in)[i];
        ushort4 o;
        o.x = f2b(v.x); o.y = f2b(v.y); o.z = f2b(v.z); o.w = f2b(v.w);
        ((ushort4*)out)[i] = o;
    }
}

// ---------- W (2048x1023 f32) -> Wt (1024x2048 bf16), row 1023 zeroed ----------
__global__ __launch_bounds__(256) void transpose_W(const float* __restrict__ W,
                                                   unsigned short* __restrict__ Wt) {
    __shared__ float tile[32][33];
    int tx = threadIdx.x, ty = threadIdx.y;
    int n0 = blockIdx.x * 32, k0 = blockIdx.y * 32;
#pragma unroll
    for (int i = 0; i < 4; i++) {
        int k = k0 + ty + i * 8, n = n0 + tx;
        tile[ty + i * 8][tx] = (n < 1023) ? W[(size_t)k * 1023 + n] : 0.f;
    }
    __syncthreads();
#pragma unroll
    for (int i = 0; i < 4; i++) {
        int n = n0 + ty + i * 8, k = k0 + tx;
        Wt[(size_t)n * 2048 + k] = f2b(tile[tx][ty + i * 8]);
    }
}

// ---------- softmax rows of leaf_dist (1024x1000) -> P bf16 (1024x1000) ----------
__global__ __launch_bounds__(256) void softmax_rows(const float* __restrict__ ld_,
                                                    unsigned short* __restrict__ P) {
    __shared__ float buf[1000];
    __shared__ float red[8];
    int t = threadIdx.x;
    const float* r = ld_ + (size_t)blockIdx.x * 1000;
    float mx = -3.4e38f;
    for (int i = t; i < 1000; i += 256) { float v = r[i]; buf[i] = v; mx = fmaxf(mx, v); }
#pragma unroll
    for (int o = 32; o > 0; o >>= 1) mx = fmaxf(mx, __shfl_down(mx, o));
    if ((t & 63) == 0) red[t >> 6] = mx;
    __syncthreads();
    mx = fmaxf(fmaxf(red[0], red[1]), fmaxf(red[2], red[3]));
    float s = 0.f;
    for (int i = t; i < 1000; i += 256) { float e = __expf(buf[i] - mx); buf[i] = e; s += e; }
#pragma unroll
    for (int o = 32; o > 0; o >>= 1) s += __shfl_down(s, o);
    if ((t & 63) == 0) red[4 + (t >> 6)] = s;
    __syncthreads();
    float inv = 1.f / (red[4] + red[5] + red[6] + red[7]);
    unsigned short* out = P + (size_t)blockIdx.x * 1000;
    for (int i = t; i < 1000; i += 256) out[i] = f2b(buf[i] * inv);
}

// ---------- P (1024x1000 bf16) -> Pt (1024x1024 bf16), rows c>=1000 zero ----------
__global__ __launch_bounds__(256) void transpose_P(const unsigned short* __restrict__ P,
                                                   unsigned short* __restrict__ Pt) {
    __shared__ unsigned short tile[32][33];
    int tx = threadIdx.x, ty = threadIdx.y;
    int c0 = blockIdx.x * 32, l0 = blockIdx.y * 32;
#pragma unroll
    for (int i = 0; i < 4; i++) {
        int c = c0 + tx, l = l0 + ty + i * 8;
        tile[ty + i * 8][tx] = (c < 1000) ? P[(size_t)l * 1000 + c] : (unsigned short)0;
    }
    __syncthreads();
#pragma unroll
    for (int i = 0; i < 4; i++) {
        Pt[(size_t)(c0 + ty + i * 8) * 1024 + l0 + tx] = tile[tx][ty + i * 8];
    }
}

// ---------- tree routing: literal reference recurrence, in-place over dec ----------
__global__ __launch_bounds__(256) void pp_kernel(unsigned short* __restrict__ dec) {
    __shared__ float d[1024];
    __shared__ float pa[1024], pb[1024];
    const int t = threadIdx.x;
    unsigned short* row = dec + (size_t)blockIdx.x * 1024;
    for (int i = t; i < 1024; i += 256) d[i] = (i < 1023) ? b2f(row[i]) : 0.f;
    if (t == 0) pa[0] = 1.f;
    __syncthreads();
    float* cur = pa; float* nxt = pb;
    for (int dep = 0; dep < 10; dep++) {
        const int half = 1 << dep;
        const int len = half << 1;
        for (int j = t; j < len; j += 256) {
            int tt = j >> dep;
            int s  = j & (half - 1);
            int i2 = 2 * s + tt;
            int u  = i2 >> dep;
            int rr = i2 & (half - 1);
            float dv = d[half - 1 + rr];
            nxt[j] = cur[rr] * (u ? (1.f - dv) : dv);
        }
        __syncthreads();
        float* tmp = cur; cur = nxt; nxt = tmp;
    }
    for (int i = t; i < 1024; i += 256) row[i] = f2b(cur[i]);
}

// ---------- m97-style bf16 GEMM, A (MxK) row-major, Bt (NxK) row-major ----------
// EPI 0: sigmoid(acc + bias[col]) -> bf16, ld=1024. EPI 1: fp32 store, col<1000, ld=1000.
#define BM 128
#define BN 128
#define BK 32

template <int EPI>
__global__ __launch_bounds__(256) void gemm_bt(const unsigned short* __restrict__ A,
                                               const unsigned short* __restrict__ Bt,
                                               const float* __restrict__ bias,
                                               unsigned short* __restrict__ obf,
                                               float* __restrict__ of32,
                                               int K, int ldo) {
    __shared__ __align__(16) unsigned short As[BM * BK];
    __shared__ __align__(16) unsigned short Bs[BN * BK];
    const int tid  = threadIdx.x;
    const int lane = tid & 63;
    const int wave = tid >> 6;
    const int wr = wave >> 1, wc = wave & 1;
    const int quad = lane >> 4, l16 = lane & 15;
    const int bm = blockIdx.y * BM, bn = blockIdx.x * BN;

    const int srow = tid >> 2;          // 0..63
    const int scol = (tid & 3) * 8;     // bf16 elements

    const unsigned short* Ag = A + (size_t)(bm + srow) * K + scol;
    const unsigned short* Bg = Bt + (size_t)(bn + srow) * K + scol;
    unsigned short* AsW = As + wave * 512;   // wave-uniform LDS staging base
    unsigned short* BsW = Bs + wave * 512;

    floatx4 acc[4][4] = {};

    for (int k0 = 0; k0 < K; k0 += BK) {
        async_cp16(Ag + k0, AsW);
        async_cp16(Ag + (size_t)64 * K + k0, AsW + 2048);
        async_cp16(Bg + k0, BsW);
        async_cp16(Bg + (size_t)64 * K + k0, BsW + 2048);
        __syncthreads();   // drains vmcnt -> LDS tiles ready

        bf16x8 af[4], bfr[4];
#pragma unroll
        for (int mi = 0; mi < 4; mi++)
            af[mi] = __builtin_bit_cast(bf16x8,
                *(const ushort8v*)(As + (wr * 64 + mi * 16 + l16) * BK + quad * 8));
#pragma unroll
        for (int ni = 0; ni < 4; ni++)
            bfr[ni] = __builtin_bit_cast(bf16x8,
                *(const ushort8v*)(Bs + (wc * 64 + ni * 16 + l16) * BK + quad * 8));
#pragma unroll
        for (int mi = 0; mi < 4; mi++)
#pragma unroll
            for (int ni = 0; ni < 4; ni++)
                acc[mi][ni] = __builtin_amdgcn_mfma_f32_16x16x32_bf16(
                    af[mi], bfr[ni], acc[mi][ni], 0, 0, 0);
        __syncthreads();   // all waves done reading before next staging
    }

#pragma unroll
    for (int ni = 0; ni < 4; ni++) {
        const int col = bn + wc * 64 + ni * 16 + l16;
        float bb = 0.f;
        if constexpr (EPI == 0) bb = (col < 1023) ? bias[col] : 0.f;
#pragma unroll
        for (int mi = 0; mi < 4; mi++) {
            const int row0 = bm + wr * 64 + mi * 16 + quad * 4;
#pragma unroll
            for (int r = 0; r < 4; r++) {
                float v = acc[mi][ni][r];
                if constexpr (EPI == 0) {
                    float sgm = 1.f / (1.f + __expf(-(v + bb)));
                    obf[(size_t)(row0 + r) * ldo + col] = f2b(sgm);
                } else {
                    if (col < 1000) of32[(size_t)(row0 + r) * ldo + col] = v;
                }
            }
        }
    }
}

// ---------- host ----------
extern "C" void kernel_launch(void* const* d_in, const int* in_sizes, int n_in,
                              void* d_out, int out_size, void* d_ws, size_t ws_size,
                              hipStream_t stream) {
    const float* x   = (const float*)d_in[0];   // 8192x2048
    const float* W   = (const float*)d_in[1];   // 2048x1023
    const float* b   = (const float*)d_in[2];   // 1023
    const float* ldd = (const float*)d_in[3];   // 1024x1000
    float* out = (float*)d_out;                 // 8192x1000

    char* ws = (char*)d_ws;
    unsigned short* xb  = (unsigned short*)(ws);              // 8192x2048 bf16 (33554432 B)
    unsigned short* Wt  = (unsigned short*)(ws + 33554432);   // 1024x2048 bf16 (4194304 B)
    unsigned short* dec = (unsigned short*)(ws + 37748736);   // 8192x1024 bf16 (16777216 B) dec->pp in place
    unsigned short* P   = (unsigned short*)(ws + 54525952);   // 1024x1000 bf16 (2048000 B, pad 2048256)
    unsigned short* Pt  = (unsigned short*)(ws + 56574208);   // 1024x1024 bf16 (2097152 B) total ~58.7 MB

    cvt_f32_bf16<<<16384, 256, 0, stream>>>(x, xb, 4194304);
    transpose_W<<<dim3(32, 64), dim3(32, 8), 0, stream>>>(W, Wt);
    softmax_rows<<<1024, 256, 0, stream>>>(ldd, P);
    transpose_P<<<dim3(32, 32), dim3(32, 8), 0, stream>>>(P, Pt);

    // decisions = sigmoid(x@W + b), padded to 1024 cols
    gemm_bt<0><<<dim3(8, 64), 256, 0, stream>>>(xb, Wt, b, dec, nullptr, 2048, 1024);
    // pp (reference-literal shuffle order), in place
    pp_kernel<<<8192, 256, 0, stream>>>(dec);
    // out = pp @ P^T^T  (Pt is P transposed)
    gemm_bt<1><<<dim3(8, 64), 256, 0, stream>>>(dec, Pt, nullptr, nullptr, out, 1024, 1000);
}

// Round 2
// 227.890 us; speedup vs baseline: 1.0346x; 1.0346x over previous
//
#include <hip/hip_runtime.h>

// ---------- common helpers ----------
typedef __attribute__((ext_vector_type(8))) unsigned short ushort8v;
typedef __attribute__((ext_vector_type(8))) __bf16 bf16x8;
typedef __attribute__((ext_vector_type(4))) float floatx4;

__device__ __forceinline__ unsigned short f2b(float f) {
    unsigned u = __float_as_uint(f);
    unsigned r = u + 0x7fffu + ((u >> 16) & 1u);   // RNE; inputs are finite/small
    return (unsigned short)(r >> 16);
}
__device__ __forceinline__ float b2f(unsigned short h) {
    return __uint_as_float(((unsigned)h) << 16);
}

__device__ __forceinline__ void async_cp16(const void* g, void* l) {
    __builtin_amdgcn_global_load_lds(
        (__attribute__((address_space(1))) void*)g,
        (__attribute__((address_space(3))) void*)l,
        16, 0, 0);
}

// ---------- x fp32 -> bf16 ----------
__global__ __launch_bounds__(256) void cvt_f32_bf16(const float* __restrict__ in,
                                                    unsigned short* __restrict__ out,
                                                    int n4) {
    int i = blockIdx.x * 256 + threadIdx.x;
    if (i < n4) {
        float4 v = ((const float4*)in)[i];
        ushort4 o;
        o.x = f2b(v.x); o.y = f2b(v.y); o.z = f2b(v.z); o.w = f2b(v.w);
        ((ushort4*)out)[i] = o;
    }
}

// ---------- W (2048x1023 f32) -> Wt (1024x2048 bf16), row 1023 zeroed ----------
__global__ __launch_bounds__(256) void transpose_W(const float* __restrict__ W,
                                                   unsigned short* __restrict__ Wt) {
    __shared__ float tile[32][33];
    int tx = threadIdx.x, ty = threadIdx.y;
    int n0 = blockIdx.x * 32, k0 = blockIdx.y * 32;
#pragma unroll
    for (int i = 0; i < 4; i++) {
        int k = k0 + ty + i * 8, n = n0 + tx;
        tile[ty + i * 8][tx] = (n < 1023) ? W[(size_t)k * 1023 + n] : 0.f;
    }
    __syncthreads();
#pragma unroll
    for (int i = 0; i < 4; i++) {
        int n = n0 + ty + i * 8, k = k0 + tx;
        Wt[(size_t)n * 2048 + k] = f2b(tile[tx][ty + i * 8]);
    }
}

// ---------- softmax rows of leaf_dist (1024x1000) -> P bf16 (1024x1000) ----------
__global__ __launch_bounds__(256) void softmax_rows(const float* __restrict__ ld_,
                                                    unsigned short* __restrict__ P) {
    __shared__ float buf[1000];
    __shared__ float red[8];
    int t = threadIdx.x;
    const float* r = ld_ + (size_t)blockIdx.x * 1000;
    float mx = -3.4e38f;
    for (int i = t; i < 1000; i += 256) { float v = r[i]; buf[i] = v; mx = fmaxf(mx, v); }
#pragma unroll
    for (int o = 32; o > 0; o >>= 1) mx = fmaxf(mx, __shfl_down(mx, o));
    if ((t & 63) == 0) red[t >> 6] = mx;
    __syncthreads();
    mx = fmaxf(fmaxf(red[0], red[1]), fmaxf(red[2], red[3]));
    float s = 0.f;
    for (int i = t; i < 1000; i += 256) { float e = __expf(buf[i] - mx); buf[i] = e; s += e; }
#pragma unroll
    for (int o = 32; o > 0; o >>= 1) s += __shfl_down(s, o);
    if ((t & 63) == 0) red[4 + (t >> 6)] = s;
    __syncthreads();
    float inv = 1.f / (red[4] + red[5] + red[6] + red[7]);
    unsigned short* out = P + (size_t)blockIdx.x * 1000;
    for (int i = t; i < 1000; i += 256) out[i] = f2b(buf[i] * inv);
}

// ---------- P (1024x1000 bf16) -> Pt (1024x1024 bf16), rows c>=1000 zero ----------
__global__ __launch_bounds__(256) void transpose_P(const unsigned short* __restrict__ P,
                                                   unsigned short* __restrict__ Pt) {
    __shared__ unsigned short tile[32][33];
    int tx = threadIdx.x, ty = threadIdx.y;
    int c0 = blockIdx.x * 32, l0 = blockIdx.y * 32;
#pragma unroll
    for (int i = 0; i < 4; i++) {
        int c = c0 + tx, l = l0 + ty + i * 8;
        tile[ty + i * 8][tx] = (c < 1000) ? P[(size_t)l * 1000 + c] : (unsigned short)0;
    }
    __syncthreads();
#pragma unroll
    for (int i = 0; i < 4; i++) {
        Pt[(size_t)(c0 + ty + i * 8) * 1024 + l0 + tx] = tile[tx][ty + i * 8];
    }
}

// ---------- tree routing: literal reference recurrence, in-place over dec ----------
__global__ __launch_bounds__(256) void pp_kernel(unsigned short* __restrict__ dec) {
    __shared__ float d[1024];
    __shared__ float pa[1024], pb[1024];
    const int t = threadIdx.x;
    unsigned short* row = dec + (size_t)blockIdx.x * 1024;
    for (int i = t; i < 1024; i += 256) d[i] = (i < 1023) ? b2f(row[i]) : 0.f;
    if (t == 0) pa[0] = 1.f;
    __syncthreads();
    float* cur = pa; float* nxt = pb;
    for (int dep = 0; dep < 10; dep++) {
        const int half = 1 << dep;
        const int len = half << 1;
        for (int j = t; j < len; j += 256) {
            int tt = j >> dep;
            int s  = j & (half - 1);
            int i2 = 2 * s + tt;
            int u  = i2 >> dep;
            int rr = i2 & (half - 1);
            float dv = d[half - 1 + rr];
            nxt[j] = cur[rr] * (u ? (1.f - dv) : dv);
        }
        __syncthreads();
        float* tmp = cur; cur = nxt; nxt = tmp;
    }
    for (int i = t; i < 1024; i += 256) row[i] = f2b(cur[i]);
}

// ---------- m97-style bf16 GEMM, A (MxK) row-major, Bt (NxK) row-major ----------
// Grid: flat 512 blocks = 64 bm x 8 bn, XCD-swizzled so XCD g owns bm in [8g, 8g+8)
// for ALL bn (A-tiles fetched once per XCD-disjoint set; B fully L2-resident/XCD).
// LDS layout XOR-swizzled: physical col-group pg holds logical group pg ^ ((row>>1)&3)
// -> fragment ds_read_b128 lands on 8 distinct banks x 2 lanes = conflict-free.
// EPI 0: sigmoid(acc + bias[col]) -> bf16, ld=1024. EPI 1: fp32 store, col<1000.
#define BM 128
#define BN 128
#define BK 32

template <int EPI>
__global__ __launch_bounds__(256) void gemm_bt(const unsigned short* __restrict__ A,
                                               const unsigned short* __restrict__ Bt,
                                               const float* __restrict__ bias,
                                               unsigned short* __restrict__ obf,
                                               float* __restrict__ of32,
                                               int K, int ldo) {
    __shared__ __align__(16) unsigned short As[BM * BK];
    __shared__ __align__(16) unsigned short Bs[BN * BK];
    const int tid  = threadIdx.x;
    const int lane = tid & 63;
    const int wave = tid >> 6;
    const int wr = wave >> 1, wc = wave & 1;
    const int quad = lane >> 4, l16 = lane & 15;

    // XCD-aware decode: linear id l -> xcd = l%8 (dispatch heuristic), so give
    // each xcd a contiguous bm-range and all 8 bn.
    const int l   = blockIdx.x;
    const int xcd = l & 7;
    const int j   = l >> 3;            // 0..63
    const int bm  = (xcd * 8 + (j & 7)) * BM;
    const int bn  = (j >> 3) * BN;

    const int srow = tid >> 2;                       // 0..63
    const int lg   = (tid & 3) ^ ((srow >> 1) & 3);  // swizzled logical col-group
    const int scol = lg * 8;

    const unsigned short* Ag = A + (size_t)(bm + srow) * K + scol;
    const unsigned short* Bg = Bt + (size_t)(bn + srow) * K + scol;
    unsigned short* AsW = As + wave * 512;   // wave-uniform LDS staging base
    unsigned short* BsW = Bs + wave * 512;

    // fragment read: physical group = quad ^ ((l16>>1)&3), wave-constant per lane
    const int pgA = (quad ^ ((l16 >> 1) & 3)) * 8;

    floatx4 acc[4][4] = {};

    for (int k0 = 0; k0 < K; k0 += BK) {
        async_cp16(Ag + k0, AsW);
        async_cp16(Ag + (size_t)64 * K + k0, AsW + 2048);
        async_cp16(Bg + k0, BsW);
        async_cp16(Bg + (size_t)64 * K + k0, BsW + 2048);
        __syncthreads();   // drains vmcnt -> LDS tiles ready

        bf16x8 af[4], bfr[4];
#pragma unroll
        for (int mi = 0; mi < 4; mi++)
            af[mi] = __builtin_bit_cast(bf16x8,
                *(const ushort8v*)(As + (wr * 64 + mi * 16 + l16) * BK + pgA));
#pragma unroll
        for (int ni = 0; ni < 4; ni++)
            bfr[ni] = __builtin_bit_cast(bf16x8,
                *(const ushort8v*)(Bs + (wc * 64 + ni * 16 + l16) * BK + pgA));
#pragma unroll
        for (int mi = 0; mi < 4; mi++)
#pragma unroll
            for (int ni = 0; ni < 4; ni++)
                acc[mi][ni] = __builtin_amdgcn_mfma_f32_16x16x32_bf16(
                    af[mi], bfr[ni], acc[mi][ni], 0, 0, 0);
        __syncthreads();   // all waves done reading before next staging
    }

#pragma unroll
    for (int ni = 0; ni < 4; ni++) {
        const int col = bn + wc * 64 + ni * 16 + l16;
        float bb = 0.f;
        if constexpr (EPI == 0) bb = (col < 1023) ? bias[col] : 0.f;
#pragma unroll
        for (int mi = 0; mi < 4; mi++) {
            const int row0 = bm + wr * 64 + mi * 16 + quad * 4;
#pragma unroll
            for (int r = 0; r < 4; r++) {
                float v = acc[mi][ni][r];
                if constexpr (EPI == 0) {
                    float sgm = 1.f / (1.f + __expf(-(v + bb)));
                    obf[(size_t)(row0 + r) * ldo + col] = f2b(sgm);
                } else {
                    if (col < 1000) of32[(size_t)(row0 + r) * ldo + col] = v;
                }
            }
        }
    }
}

// ---------- host ----------
extern "C" void kernel_launch(void* const* d_in, const int* in_sizes, int n_in,
                              void* d_out, int out_size, void* d_ws, size_t ws_size,
                              hipStream_t stream) {
    const float* x   = (const float*)d_in[0];   // 8192x2048
    const float* W   = (const float*)d_in[1];   // 2048x1023
    const float* b   = (const float*)d_in[2];   // 1023
    const float* ldd = (const float*)d_in[3];   // 1024x1000
    float* out = (float*)d_out;                 // 8192x1000

    char* ws = (char*)d_ws;
    unsigned short* xb  = (unsigned short*)(ws);              // 8192x2048 bf16 (33554432 B)
    unsigned short* Wt  = (unsigned short*)(ws + 33554432);   // 1024x2048 bf16 (4194304 B)
    unsigned short* dec = (unsigned short*)(ws + 37748736);   // 8192x1024 bf16 (16777216 B) dec->pp in place
    unsigned short* P   = (unsigned short*)(ws + 54525952);   // 1024x1000 bf16 (2048000 B, pad 2048256)
    unsigned short* Pt  = (unsigned short*)(ws + 56574208);   // 1024x1024 bf16 (2097152 B) total ~58.7 MB

    cvt_f32_bf16<<<16384, 256, 0, stream>>>(x, xb, 4194304);
    transpose_W<<<dim3(32, 64), dim3(32, 8), 0, stream>>>(W, Wt);
    softmax_rows<<<1024, 256, 0, stream>>>(ldd, P);
    transpose_P<<<dim3(32, 32), dim3(32, 8), 0, stream>>>(P, Pt);

    // decisions = sigmoid(x@W + b), padded to 1024 cols
    gemm_bt<0><<<512, 256, 0, stream>>>(xb, Wt, b, dec, nullptr, 2048, 1024);
    // pp (reference-literal shuffle order), in place
    pp_kernel<<<8192, 256, 0, stream>>>(dec);
    // out = pp @ P^T^T  (Pt is P transposed)
    gemm_bt<1><<<512, 256, 0, stream>>>(dec, Pt, nullptr, nullptr, out, 1024, 1000);
}

// Round 3
// 219.441 us; speedup vs baseline: 1.0745x; 1.0385x over previous
//
#include <hip/hip_runtime.h>

// ---------- common helpers ----------
typedef __attribute__((ext_vector_type(8))) unsigned short ushort8v;
typedef __attribute__((ext_vector_type(8))) __bf16 bf16x8;
typedef __attribute__((ext_vector_type(4))) float floatx4;

__device__ __forceinline__ unsigned short f2b(float f) {
    unsigned u = __float_as_uint(f);
    unsigned r = u + 0x7fffu + ((u >> 16) & 1u);   // RNE
    return (unsigned short)(r >> 16);
}
__device__ __forceinline__ float b2f(unsigned short h) {
    return __uint_as_float(((unsigned)h) << 16);
}

__device__ __forceinline__ void async_cp16(const void* g, void* l) {
    __builtin_amdgcn_global_load_lds(
        (__attribute__((address_space(1))) void*)g,
        (__attribute__((address_space(3))) void*)l,
        16, 0, 0);
}

// ---------- fused prep: cvt x (16384 blocks) | transpose_W (2048) | softmax (1024) ----------
__global__ __launch_bounds__(256) void prep_kernel(const float* __restrict__ x,
                                                   unsigned short* __restrict__ xb,
                                                   const float* __restrict__ W,
                                                   unsigned short* __restrict__ Wt,
                                                   const float* __restrict__ ld_,
                                                   unsigned short* __restrict__ P) {
    __shared__ float tile[32 * 33];
    __shared__ float buf[1000];
    __shared__ float red[8];
    const int b = blockIdx.x, t = threadIdx.x;
    if (b < 16384) {                       // ---- cvt x fp32 -> bf16 (float4) ----
        int i = b * 256 + t;
        float4 v = ((const float4*)x)[i];
        ushort4 o;
        o.x = f2b(v.x); o.y = f2b(v.y); o.z = f2b(v.z); o.w = f2b(v.w);
        ((ushort4*)xb)[i] = o;
    } else if (b < 16384 + 2048) {         // ---- W (2048x1023) -> Wt (1024x2048 bf16) ----
        int idx = b - 16384;
        int n0 = (idx & 31) * 32, k0 = (idx >> 5) * 32;
        int tx = t & 31, ty = t >> 5;
#pragma unroll
        for (int i = 0; i < 4; i++) {
            int k = k0 + ty + i * 8, n = n0 + tx;
            tile[(ty + i * 8) * 33 + tx] = (n < 1023) ? W[(size_t)k * 1023 + n] : 0.f;
        }
        __syncthreads();
#pragma unroll
        for (int i = 0; i < 4; i++) {
            int n = n0 + ty + i * 8, k = k0 + tx;
            Wt[(size_t)n * 2048 + k] = f2b(tile[tx * 33 + ty + i * 8]);
        }
    } else {                               // ---- softmax rows of leaf_dist -> P bf16 ----
        int row = b - 18432;
        const float* r = ld_ + (size_t)row * 1000;
        float mx = -3.4e38f;
        for (int i = t; i < 1000; i += 256) { float v = r[i]; buf[i] = v; mx = fmaxf(mx, v); }
#pragma unroll
        for (int o = 32; o > 0; o >>= 1) mx = fmaxf(mx, __shfl_down(mx, o));
        if ((t & 63) == 0) red[t >> 6] = mx;
        __syncthreads();
        mx = fmaxf(fmaxf(red[0], red[1]), fmaxf(red[2], red[3]));
        float s = 0.f;
        for (int i = t; i < 1000; i += 256) { float e = __expf(buf[i] - mx); buf[i] = e; s += e; }
#pragma unroll
        for (int o = 32; o > 0; o >>= 1) s += __shfl_down(s, o);
        if ((t & 63) == 0) red[4 + (t >> 6)] = s;
        __syncthreads();
        float inv = 1.f / (red[4] + red[5] + red[6] + red[7]);
        unsigned short* out = P + (size_t)row * 1000;
        for (int i = t; i < 1000; i += 256) out[i] = f2b(buf[i] * inv);
    }
}

// ---------- fused: pp tree routing (8192 blocks) | transpose_P (1024 blocks) ----------
__global__ __launch_bounds__(256) void pp_transP_kernel(unsigned short* __restrict__ dec,
                                                        const unsigned short* __restrict__ P,
                                                        unsigned short* __restrict__ Pt) {
    __shared__ float smem[3072];           // pp: d|pa|pb ; transP: ushort tile[32][33]
    const int b = blockIdx.x, t = threadIdx.x;
    if (b < 8192) {                        // ---- pp: literal reference recurrence ----
        float* d = smem; float* pa = smem + 1024; float* pb = smem + 2048;
        unsigned short* row = dec + (size_t)b * 1024;
        for (int i = t; i < 1024; i += 256) d[i] = (i < 1023) ? b2f(row[i]) : 0.f;
        if (t == 0) pa[0] = 1.f;
        __syncthreads();
        float* cur = pa; float* nxt = pb;
        for (int dep = 0; dep < 10; dep++) {
            const int half = 1 << dep;
            const int len = half << 1;
            for (int j = t; j < len; j += 256) {
                int tt = j >> dep;
                int s  = j & (half - 1);
                int i2 = 2 * s + tt;
                int u  = i2 >> dep;
                int rr = i2 & (half - 1);
                float dv = d[half - 1 + rr];
                nxt[j] = cur[rr] * (u ? (1.f - dv) : dv);
            }
            __syncthreads();
            float* tmp = cur; cur = nxt; nxt = tmp;
        }
        for (int i = t; i < 1024; i += 256) row[i] = f2b(cur[i]);
    } else {                               // ---- P (1024x1000) -> Pt (1024x1024), zero-pad ----
        int idx = b - 8192;
        int c0 = (idx & 31) * 32, l0 = (idx >> 5) * 32;
        int tx = t & 31, ty = t >> 5;
        unsigned short* tile = (unsigned short*)smem;
#pragma unroll
        for (int i = 0; i < 4; i++) {
            int c = c0 + tx, l = l0 + ty + i * 8;
            tile[(ty + i * 8) * 33 + tx] = (c < 1000) ? P[(size_t)l * 1000 + c] : (unsigned short)0;
        }
        __syncthreads();
#pragma unroll
        for (int i = 0; i < 4; i++) {
            Pt[(size_t)(c0 + ty + i * 8) * 1024 + l0 + tx] = tile[tx * 33 + ty + i * 8];
        }
    }
}

// ---------- bf16 GEMM, A (MxK) row-major, Bt (NxK) row-major ----------
// Tile 64x128, grid 1024 blocks = 4/CU (occupancy was the R2 limiter at 2/CU).
// XCD swizzle: xcd g owns bm-tiles [16g,16g+16) for all bn -> A fetched once/XCD.
// LDS XOR swizzle (verified conflict-free in R2: SQ_LDS_BANK_CONFLICT=0).
// EPI 0: sigmoid(acc + bias[col]) -> bf16, ld=1024. EPI 1: fp32 store, col<1000.
#define BM 64
#define BN 128
#define BK 32

template <int EPI>
__global__ __launch_bounds__(256, 4) void gemm_bt(const unsigned short* __restrict__ A,
                                                  const unsigned short* __restrict__ Bt,
                                                  const float* __restrict__ bias,
                                                  unsigned short* __restrict__ obf,
                                                  float* __restrict__ of32,
                                                  int K, int ldo) {
    __shared__ __align__(16) unsigned short As[BM * BK];   // 4 KB
    __shared__ __align__(16) unsigned short Bs[BN * BK];   // 8 KB
    const int tid  = threadIdx.x;
    const int lane = tid & 63;
    const int wave = tid >> 6;
    const int wrow = (wave >> 1) * 32;     // wave covers 32 rows x 64 cols
    const int wcol = (wave & 1) * 64;
    const int quad = lane >> 4, l16 = lane & 15;

    // XCD-aware decode: 1024 blocks = 128 bm-tiles x 8 bn-tiles
    const int l   = blockIdx.x;
    const int xcd = l & 7;
    const int j   = l >> 3;                    // 0..127
    const int bm  = (xcd * 16 + (j & 15)) * BM;
    const int bn  = (j >> 4) * BN;

    const int srow = tid >> 2;                       // 0..63
    const int lg   = (tid & 3) ^ ((srow >> 1) & 3);  // swizzled logical col-group
    const int scol = lg * 8;

    const unsigned short* Ag = A + (size_t)(bm + srow) * K + scol;
    const unsigned short* Bg = Bt + (size_t)(bn + srow) * K + scol;
    unsigned short* AsW = As + wave * 512;   // wave-uniform staging bases
    unsigned short* BsW = Bs + wave * 512;

    const int pg = (quad ^ ((l16 >> 1) & 3)) * 8;   // physical group at read

    floatx4 acc[2][4] = {};

    for (int k0 = 0; k0 < K; k0 += BK) {
        async_cp16(Ag + k0, AsW);
        async_cp16(Bg + k0, BsW);
        async_cp16(Bg + (size_t)64 * K + k0, BsW + 2048);
        __syncthreads();   // drains vmcnt -> tiles ready

        bf16x8 af[2], bfr[4];
#pragma unroll
        for (int mi = 0; mi < 2; mi++)
            af[mi] = __builtin_bit_cast(bf16x8,
                *(const ushort8v*)(As + (wrow + mi * 16 + l16) * BK + pg));
#pragma unroll
        for (int ni = 0; ni < 4; ni++)
            bfr[ni] = __builtin_bit_cast(bf16x8,
                *(const ushort8v*)(Bs + (wcol + ni * 16 + l16) * BK + pg));
#pragma unroll
        for (int mi = 0; mi < 2; mi++)
#pragma unroll
            for (int ni = 0; ni < 4; ni++)
                acc[mi][ni] = __builtin_amdgcn_mfma_f32_16x16x32_bf16(
                    af[mi], bfr[ni], acc[mi][ni], 0, 0, 0);
        __syncthreads();
    }

#pragma unroll
    for (int ni = 0; ni < 4; ni++) {
        const int col = bn + wcol + ni * 16 + l16;
        float bb = 0.f;
        if constexpr (EPI == 0) bb = (col < 1023) ? bias[col] : 0.f;
#pragma unroll
        for (int mi = 0; mi < 2; mi++) {
            const int row0 = bm + wrow + mi * 16 + quad * 4;
#pragma unroll
            for (int r = 0; r < 4; r++) {
                float v = acc[mi][ni][r];
                if constexpr (EPI == 0) {
                    float sgm = 1.f / (1.f + __expf(-(v + bb)));
                    obf[(size_t)(row0 + r) * ldo + col] = f2b(sgm);
                } else {
                    if (col < 1000) of32[(size_t)(row0 + r) * ldo + col] = v;
                }
            }
        }
    }
}

// ---------- host ----------
extern "C" void kernel_launch(void* const* d_in, const int* in_sizes, int n_in,
                              void* d_out, int out_size, void* d_ws, size_t ws_size,
                              hipStream_t stream) {
    const float* x   = (const float*)d_in[0];   // 8192x2048
    const float* W   = (const float*)d_in[1];   // 2048x1023
    const float* b   = (const float*)d_in[2];   // 1023
    const float* ldd = (const float*)d_in[3];   // 1024x1000
    float* out = (float*)d_out;                 // 8192x1000

    char* ws = (char*)d_ws;
    unsigned short* xb  = (unsigned short*)(ws);              // 8192x2048 bf16
    unsigned short* Wt  = (unsigned short*)(ws + 33554432);   // 1024x2048 bf16
    unsigned short* dec = (unsigned short*)(ws + 37748736);   // 8192x1024 bf16 (in-place pp)
    unsigned short* P   = (unsigned short*)(ws + 54525952);   // 1024x1000 bf16
    unsigned short* Pt  = (unsigned short*)(ws + 56574208);   // 1024x1024 bf16

    // prep: cvt | transpose_W | softmax  (independent, one launch)
    prep_kernel<<<16384 + 2048 + 1024, 256, 0, stream>>>(x, xb, W, Wt, ldd, P);
    // decisions = sigmoid(x@W + b), padded to 1024 cols
    gemm_bt<0><<<1024, 256, 0, stream>>>(xb, Wt, b, dec, nullptr, 2048, 1024);
    // pp (reference-literal order, in place) | transpose_P  (independent, one launch)
    pp_transP_kernel<<<8192 + 1024, 256, 0, stream>>>(dec, P, Pt);
    // out = pp @ P
    gemm_bt<1><<<1024, 256, 0, stream>>>(dec, Pt, nullptr, nullptr, out, 1024, 1000);
}